// Round 3
// baseline (670.284 us; speedup 1.0000x reference)
//
#include <hip/hip_runtime.h>
#include <hip/hip_bf16.h>

#define LB   9216          // sequence length per batch (96*96)
#define NB   2             // batch
#define ROWS (NB*LB)       // 18432 rows
#define NCH  96            // scan chunks per batch
#define CHL  96            // chunk length

typedef __hip_bfloat16  bf16;
typedef __hip_bfloat162 bf162;

__device__ __forceinline__ float silu_f(float v) { return v / (1.f + __expf(-v)); }
__device__ __forceinline__ float softplus_f(float v) {
    return fmaxf(v, 0.f) + log1pf(__expf(-fabsf(v)));
}

// ---------------------------------------------------------------------------
// K0a: dtype probe. A_log[0] = log(1) = 0.0: first u32 is 0x00000000 iff f32.
__global__ void k_probe(const void* __restrict__ alog_raw, int* __restrict__ mode) {
    if (threadIdx.x == 0 && blockIdx.x == 0)
        *mode = (*(const unsigned int*)alog_raw != 0u) ? 1 : 0;   // 1 = bf16, 0 = f32
}

// K0b: convert all 18 inputs to f32 in workspace (dtype-agnostic pipeline).
struct CvtArgs { const void* src[18]; int off[19]; };
__global__ void k_convert(CvtArgs a, const int* __restrict__ mode,
                          float* __restrict__ dst, int total) {
    int i = blockIdx.x * 256 + threadIdx.x;
    if (i >= total) return;
    int s = 0;
    while (i >= a.off[s + 1]) ++s;
    int j = i - a.off[s];
    float v;
    if (*mode) v = __bfloat162float(((const bf16*)a.src[s])[j]);
    else       v = ((const float*)a.src[s])[j];
    dst[i] = v;
}

// ---------------------------------------------------------------------------
// K1: expand GEMM (128->256) + pixel-shuffle + LN(64) + concat skip -> x0 f32
// one block (64 threads = 1 wave) per output pixel
__global__ void k_expand(const float* __restrict__ x, const float* __restrict__ skip,
                         const float* __restrict__ ew, const float* __restrict__ peg,
                         const float* __restrict__ peb, float* __restrict__ x0) {
    int row = blockIdx.x;            // b*9216 + h2*96 + w2
    int t = threadIdx.x;             // 0..63
    int b = row / LB;
    int l = row - b * LB;
    int h2 = l / 96, w2 = l - h2 * 96;
    int h = h2 >> 1, w = w2 >> 1;
    int q = ((h2 & 1) << 1) | (w2 & 1);
    __shared__ float xv[128];
    const int xbase = b * (128 * 48 * 48) + h * 48 + w;
    xv[t]      = x[xbase + t * 2304];
    xv[t + 64] = x[xbase + (t + 64) * 2304];
    __syncthreads();
    int col = q * 64 + t;
    float acc = 0.f;
    #pragma unroll 8
    for (int k = 0; k < 128; ++k)
        acc += xv[k] * ew[k * 256 + col];
    float s = acc, sq = acc * acc;
    #pragma unroll
    for (int m = 32; m >= 1; m >>= 1) {
        s  += __shfl_xor(s, m);
        sq += __shfl_xor(sq, m);
    }
    float mu  = s * (1.f / 64.f);
    float var = sq * (1.f / 64.f) - mu * mu;
    float rs  = rsqrtf(var + 1e-5f);
    float val = (acc - mu) * rs * peg[t] + peb[t];
    x0[row * 128 + t]      = val;
    x0[row * 128 + 64 + t] = skip[b * (64 * 96 * 96) + t * 9216 + h2 * 96 + w2];
}

// ---------------------------------------------------------------------------
// K2: fused LN(128) + in_proj(128->512) + causal conv4 + SiLU -> xc (bf16),
//     z half -> z (bf16). 16 output rows/block; 3 overlap rows recomputed for conv.
__global__ void k_fused_in(const float* __restrict__ x0, const float* __restrict__ g,
                           const float* __restrict__ bb, const float* __restrict__ ipw,
                           const float* __restrict__ cw, const float* __restrict__ cb,
                           bf16* __restrict__ xc, bf16* __restrict__ z, int dep) {
    __shared__ __align__(16) float a[19 * 128];
    int row0 = blockIdx.x * 16;
    int l0 = row0 % LB;              // 0 only at batch starts (LB%16==0)
    int t = threadIdx.x;             // 256
    int wv = t >> 6, lane = t & 63;
    for (int j = wv; j < 19; j += 4) {
        int gr = row0 - 3 + j;
        bool valid = !(l0 == 0 && j < 3);
        float v0 = 0.f, v1 = 0.f;
        if (valid) { v0 = x0[gr * 128 + lane]; v1 = x0[gr * 128 + 64 + lane]; }
        float s = v0 + v1, sq = v0 * v0 + v1 * v1;
        #pragma unroll
        for (int m = 32; m >= 1; m >>= 1) { s += __shfl_xor(s, m); sq += __shfl_xor(sq, m); }
        float mu  = s * (1.f / 128.f);
        float var = sq * (1.f / 128.f) - mu * mu;
        float rs  = rsqrtf(var + 1e-5f);
        float o0 = 0.f, o1 = 0.f;
        if (valid) {
            o0 = (v0 - mu) * rs * g[dep * 128 + lane]      + bb[dep * 128 + lane];
            o1 = (v1 - mu) * rs * g[dep * 128 + 64 + lane] + bb[dep * 128 + 64 + lane];
        }
        a[j * 128 + lane]      = o0;
        a[j * 128 + 64 + lane] = o1;
    }
    __syncthreads();
    // GEMM: thread t owns output cols {2t, 2t+1}; rows 0..18
    const float2* wp = (const float2*)(ipw + (size_t)dep * 128 * 512);
    float acc0[19], acc1[19];
    #pragma unroll
    for (int j = 0; j < 19; ++j) { acc0[j] = 0.f; acc1[j] = 0.f; }
    for (int k = 0; k < 128; k += 4) {
        float w0[4], w1[4];
        #pragma unroll
        for (int u = 0; u < 4; ++u) {
            float2 wv2 = wp[(k + u) * 256 + t];
            w0[u] = wv2.x;
            w1[u] = wv2.y;
        }
        #pragma unroll
        for (int j = 0; j < 19; ++j) {
            const float4 av = *(const float4*)&a[j * 128 + k];
            acc0[j] += av.x * w0[0]; acc0[j] += av.y * w0[1];
            acc0[j] += av.z * w0[2]; acc0[j] += av.w * w0[3];
            acc1[j] += av.x * w1[0]; acc1[j] += av.y * w1[1];
            acc1[j] += av.z * w1[2]; acc1[j] += av.w * w1[3];
        }
    }
    if (t < 128) {
        int d0 = 2 * t;
        float cw0[4], cw1[4];
        #pragma unroll
        for (int k = 0; k < 4; ++k) {
            cw0[k] = cw[dep * 1024 + d0 * 4 + k];
            cw1[k] = cw[dep * 1024 + (d0 + 1) * 4 + k];
        }
        float cb0 = cb[dep * 256 + d0], cb1 = cb[dep * 256 + d0 + 1];
        bf162* xc2 = (bf162*)xc;
        #pragma unroll
        for (int i = 0; i < 16; ++i) {
            float s0 = cb0, s1 = cb1;
            #pragma unroll
            for (int k = 0; k < 4; ++k) { s0 += acc0[i + k] * cw0[k]; s1 += acc1[i + k] * cw1[k]; }
            s0 = silu_f(s0); s1 = silu_f(s1);
            bf162 pk; pk.x = __float2bfloat16(s0); pk.y = __float2bfloat16(s1);
            xc2[(row0 + i) * 128 + t] = pk;
        }
    } else {
        bf162* z2 = (bf162*)z;
        int c = t - 128;
        #pragma unroll
        for (int i = 0; i < 16; ++i) {
            bf162 pk; pk.x = __float2bfloat16(acc0[i + 3]); pk.y = __float2bfloat16(acc1[i + 3]);
            z2[(row0 + i) * 128 + c] = pk;
        }
    }
}

// ---------------------------------------------------------------------------
// K3: x_proj (256->40) + split + dt = softplus(dtlow@dt_w + dt_b). one block/row.
__global__ void k_xproj(const bf16* __restrict__ xc, const float* __restrict__ xpw,
                        const float* __restrict__ dtw, const float* __restrict__ dtb,
                        bf16* __restrict__ dt, bf16* __restrict__ Bm, bf16* __restrict__ Cm, int dep) {
    __shared__ float xr[256];
    __shared__ float part[160];
    __shared__ float xdbl[40];
    int row = blockIdx.x, t = threadIdx.x;   // 256 threads
    xr[t] = __bfloat162float(xc[row * 256 + t]);
    __syncthreads();
    if (t < 160) {
        int o = t % 40, seg = t / 40;
        const float* wpp = xpw + dep * 256 * 40;
        int k0 = seg * 64;
        float p = 0.f;
        for (int k = 0; k < 64; ++k)
            p += xr[k0 + k] * wpp[(k0 + k) * 40 + o];
        part[t] = p;
    }
    __syncthreads();
    if (t < 40) {
        float v = part[t] + part[40 + t] + part[80 + t] + part[120 + t];
        xdbl[t] = v;
        if (t >= 8 && t < 24)      Bm[row * 16 + t - 8]  = __float2bfloat16(v);
        else if (t >= 24)          Cm[row * 16 + t - 24] = __float2bfloat16(v);
    }
    __syncthreads();
    float acc = dtb[dep * 256 + t];
    #pragma unroll
    for (int r = 0; r < 8; ++r)
        acc += xdbl[r] * dtw[dep * 2048 + r * 256 + t];
    dt[row * 256 + t] = __float2bfloat16(softplus_f(acc));
}

// ---------------------------------------------------------------------------
// K4: scan phase 1 — per-chunk local scan: Aprod and h_end (h0=0).
__global__ void k_scan1(const bf16* __restrict__ dt, const bf16* __restrict__ xc,
                        const bf16* __restrict__ Bm, const float* __restrict__ alog,
                        float* __restrict__ hend, float* __restrict__ aprod, int dep) {
    __shared__ float dts[CHL * 16], xs[CHL * 16], Bs[CHL * 16];
    int blk = blockIdx.x;
    int b   = blk / (NCH * 16);
    int rem = blk - b * (NCH * 16);
    int ch  = rem >> 4;
    int d0  = (rem & 15) << 4;
    int t = threadIdx.x;
    int dl = t >> 4, s = t & 15;
    int rb = b * LB + ch * CHL;
    for (int j = t; j < CHL * 16; j += 256) {
        int r = j >> 4, c = j & 15;
        dts[j] = __bfloat162float(dt[(rb + r) * 256 + d0 + c]);
        xs[j]  = __bfloat162float(xc[(rb + r) * 256 + d0 + c]);
        Bs[j]  = __bfloat162float(Bm[(rb + r) * 16 + c]);
    }
    __syncthreads();
    int d = d0 + dl;
    float A = -__expf(alog[dep * 4096 + d * 16 + s]);
    float h = 0.f, ap = 1.f;
    for (int r = 0; r < CHL; ++r) {
        float dtv = dts[r * 16 + dl];
        float a = __expf(dtv * A);
        ap *= a;
        h = h * a + dtv * xs[r * 16 + dl] * Bs[r * 16 + s];
    }
    int idx = ((b * NCH + ch) * 256 + d) * 16 + s;
    hend[idx]  = h;
    aprod[idx] = ap;
}

// ---------------------------------------------------------------------------
// K5: scan phase 2 — serial scan across chunks for each (b,d,s). 8192 threads.
__global__ void k_scan2(const float* __restrict__ hend, const float* __restrict__ aprod,
                        float* __restrict__ hstart) {
    int p = blockIdx.x * 256 + threadIdx.x;   // [0, 8192)
    int b = p >> 12, rem = p & 4095;
    float h = 0.f;
    for (int ch = 0; ch < NCH; ++ch) {
        int idx = (b * NCH + ch) * 4096 + rem;
        hstart[idx] = h;
        h = h * aprod[idx] + hend[idx];
    }
}

// ---------------------------------------------------------------------------
// K6: scan phase 3 — replay with h_start, y = (scan_y + xc*D) * silu(z) -> yb bf16
__global__ void k_scan3(const bf16* __restrict__ dt, const bf16* __restrict__ xc,
                        const bf16* __restrict__ Bm, const bf16* __restrict__ Cm,
                        const bf16* __restrict__ z, const float* __restrict__ alog,
                        const float* __restrict__ Dp,
                        const float* __restrict__ hstart, bf16* __restrict__ yb, int dep) {
    __shared__ float dts[CHL * 16], xs[CHL * 16], Bs[CHL * 16], Cs[CHL * 16], zs[CHL * 16];
    int blk = blockIdx.x;
    int b   = blk / (NCH * 16);
    int rem = blk - b * (NCH * 16);
    int ch  = rem >> 4;
    int d0  = (rem & 15) << 4;
    int t = threadIdx.x;
    int dl = t >> 4, s = t & 15;
    int rb = b * LB + ch * CHL;
    for (int j = t; j < CHL * 16; j += 256) {
        int r = j >> 4, c = j & 15;
        dts[j] = __bfloat162float(dt[(rb + r) * 256 + d0 + c]);
        xs[j]  = __bfloat162float(xc[(rb + r) * 256 + d0 + c]);
        Bs[j]  = __bfloat162float(Bm[(rb + r) * 16 + c]);
        Cs[j]  = __bfloat162float(Cm[(rb + r) * 16 + c]);
        zs[j]  = __bfloat162float(z[(rb + r) * 256 + d0 + c]);
    }
    __syncthreads();
    int d = d0 + dl;
    float A  = -__expf(alog[dep * 4096 + d * 16 + s]);
    float Dv = Dp[dep * 256 + d];
    float h  = hstart[((b * NCH + ch) * 256 + d) * 16 + s];
    for (int r = 0; r < CHL; ++r) {
        float dtv = dts[r * 16 + dl];
        float a = __expf(dtv * A);
        h = h * a + dtv * xs[r * 16 + dl] * Bs[r * 16 + s];
        float p = h * Cs[r * 16 + s];
        p += __shfl_xor(p, 1);
        p += __shfl_xor(p, 2);
        p += __shfl_xor(p, 4);
        p += __shfl_xor(p, 8);
        if (s == 0) {
            float y = (p + xs[r * 16 + dl] * Dv) * silu_f(zs[r * 16 + dl]);
            yb[(rb + r) * 256 + d] = __float2bfloat16(y);
        }
    }
}

// ---------------------------------------------------------------------------
// K7: out_proj GEMM (256->128) + residual into x0. 16 rows/block.
__global__ void k_outproj(const bf16* __restrict__ yb, const float* __restrict__ w,
                          float* __restrict__ x0, int dep) {
    __shared__ float a[16 * 256];
    int row0 = blockIdx.x * 16, t = threadIdx.x;
    for (int j = t; j < 4096; j += 256) a[j] = __bfloat162float(yb[row0 * 256 + j]);
    __syncthreads();
    int col = t & 127, half = t >> 7;
    const float* wp = w + dep * 256 * 128;
    float acc[8] = {0.f, 0.f, 0.f, 0.f, 0.f, 0.f, 0.f, 0.f};
    for (int k = 0; k < 256; ++k) {
        float wvv = wp[k * 128 + col];
        #pragma unroll
        for (int r = 0; r < 8; ++r)
            acc[r] += a[(half * 8 + r) * 256 + k] * wvv;
    }
    #pragma unroll
    for (int r = 0; r < 8; ++r) {
        int row = row0 + half * 8 + r;
        x0[row * 128 + col] += acc[r];
    }
}

// ---------------------------------------------------------------------------
// K8: final GEMM (128->64) + bias -> out (dtype per mode). 4 rows/block.
__global__ void k_final(const float* __restrict__ x0, const float* __restrict__ w,
                        const float* __restrict__ bb, void* __restrict__ out,
                        const int* __restrict__ mode) {
    __shared__ float a[4 * 128];
    int row0 = blockIdx.x * 4, t = threadIdx.x;
    for (int j = t; j < 512; j += 256) a[j] = x0[row0 * 128 + j];
    __syncthreads();
    int c = t & 63, r = t >> 6;
    float acc = bb[c];
    #pragma unroll 4
    for (int k = 0; k < 128; ++k)
        acc += a[r * 128 + k] * w[k * 64 + c];
    int idx = (row0 + r) * 64 + c;
    if (*mode) ((bf16*)out)[idx] = __float2bfloat16(acc);
    else       ((float*)out)[idx] = acc;
}

// ---------------------------------------------------------------------------
extern "C" void kernel_launch(void* const* d_in, const int* in_sizes, int n_in,
                              void* d_out, int out_size, void* d_ws, size_t ws_size,
                              hipStream_t stream) {
    (void)in_sizes; (void)n_in; (void)out_size; (void)ws_size;
    static const int sz[18] = {589824, 1179648, 32768, 64, 64, 256, 256, 131072,
                               2048, 512, 20480, 4096, 512, 8192, 512, 65536, 8192, 64};
    CvtArgs ca;
    int off = 0;
    for (int i = 0; i < 18; ++i) { ca.src[i] = d_in[i]; ca.off[i] = off; off += sz[i]; }
    ca.off[18] = off;                                // 2,044,096 elements total

    // workspace layout
    int*   mode   = (int*)d_ws;                      // 256 B header
    float* wf     = (float*)((char*)d_ws + 256);     // converted inputs (f32)
    float* x0     = wf + 2044096;                    // ROWS*128 f32
    float* hend   = x0 + (size_t)ROWS * 128;         // NB*NCH*4096 f32 each
    float* aprod  = hend + (size_t)NB * NCH * 4096;
    float* hstart = aprod + (size_t)NB * NCH * 4096;
    bf16* dt = (bf16*)(hstart + (size_t)NB * NCH * 4096);
    bf16* xc = dt + (size_t)ROWS * 256;
    bf16* z  = xc + (size_t)ROWS * 256;
    bf16* yb = z  + (size_t)ROWS * 256;
    bf16* Bm = yb + (size_t)ROWS * 256;
    bf16* Cm = Bm + (size_t)ROWS * 16;

    // converted-input pointers
    const float* x    = wf + ca.off[0];
    const float* skip = wf + ca.off[1];
    const float* ew   = wf + ca.off[2];
    const float* peg  = wf + ca.off[3];
    const float* peb  = wf + ca.off[4];
    const float* lng  = wf + ca.off[5];
    const float* lnb  = wf + ca.off[6];
    const float* ipw  = wf + ca.off[7];
    const float* cw   = wf + ca.off[8];
    const float* cb   = wf + ca.off[9];
    const float* xpw  = wf + ca.off[10];
    const float* dtw  = wf + ca.off[11];
    const float* dtb  = wf + ca.off[12];
    const float* alog = wf + ca.off[13];
    const float* Dp   = wf + ca.off[14];
    const float* opw  = wf + ca.off[15];
    const float* cbw  = wf + ca.off[16];
    const float* cbb  = wf + ca.off[17];

    k_probe  <<<1, 64, 0, stream>>>(d_in[13], mode);
    k_convert<<<(ca.off[18] + 255) / 256, 256, 0, stream>>>(ca, mode, wf, ca.off[18]);
    k_expand <<<ROWS, 64, 0, stream>>>(x, skip, ew, peg, peb, x0);
    for (int dep = 0; dep < 2; ++dep) {
        k_fused_in<<<ROWS / 16, 256, 0, stream>>>(x0, lng, lnb, ipw, cw, cb, xc, z, dep);
        k_xproj  <<<ROWS,       256, 0, stream>>>(xc, xpw, dtw, dtb, dt, Bm, Cm, dep);
        k_scan1  <<<NB * NCH * 16, 256, 0, stream>>>(dt, xc, Bm, alog, hend, aprod, dep);
        k_scan2  <<<32,         256, 0, stream>>>(hend, aprod, hstart);
        k_scan3  <<<NB * NCH * 16, 256, 0, stream>>>(dt, xc, Bm, Cm, z, alog, Dp, hstart, yb, dep);
        k_outproj<<<ROWS / 16,  256, 0, stream>>>(yb, opw, x0, dep);
    }
    k_final<<<ROWS / 4, 256, 0, stream>>>(x0, cbw, cbb, d_out, mode);
}